// Round 1
// baseline (1149.015 us; speedup 1.0000x reference)
//
#include <hip/hip_runtime.h>

typedef __bf16 bf16_t;
typedef bf16_t bf16x8 __attribute__((ext_vector_type(8)));
typedef float f32x4 __attribute__((ext_vector_type(4)));

#define B_    8
#define H_    16
#define S_    16
#define D_    2048
#define HD    128
#define CL    4096
#define TL    4112
#define NCH   17        // 16 cache chunks + 1 "new keys" chunk
#define CHUNK 256
#define PSTRIDE 2080    // per (bh,chunk) partial: m[16], l[16], O[16][128]
#define SCALE 0.08838834764831845f  // 1/sqrt(128)

__device__ inline f32x4 mfma16(bf16x8 a, bf16x8 b, f32x4 c) {
  return __builtin_amdgcn_mfma_f32_16x16x32_bf16(a, b, c, 0, 0, 0);
}

__device__ inline bf16x8 cvt8(f32x4 a, f32x4 b) {
  bf16x8 r;
  r[0] = (bf16_t)a[0]; r[1] = (bf16_t)a[1]; r[2] = (bf16_t)a[2]; r[3] = (bf16_t)a[3];
  r[4] = (bf16_t)b[0]; r[5] = (bf16_t)b[1]; r[6] = (bf16_t)b[2]; r[7] = (bf16_t)b[3];
  return r;
}

// ---------------------------------------------------------------------------
// GEMM: A[128 x 2048] @ W[2048 x N] + bias.
// MODE 1 (QKV): N=6144, A=x (fp32). cols 0..2047 -> q_ws (bf16);
//               2048..4095 -> kh tail (fp32); 4096..6143 -> vh tail (fp32).
// MODE 0 (proj): N=2048, A=ctx (bf16). -> out (fp32).
// Block: 256 thr = 4 waves; block tile 64 rows x 64 cols; wave tile 16x64.
// B tile staged to LDS transposed (bf16) so B-frags are ds_read_b128.
// ---------------------------------------------------------------------------
template <bool ABF16, int MODE>
__global__ __launch_bounds__(256)
void gemm_k(const void* __restrict__ Ap_, const float* __restrict__ W,
            const float* __restrict__ bias, bf16_t* __restrict__ qout,
            float* __restrict__ khout, float* __restrict__ vhout,
            float* __restrict__ outp, int N) {
  __shared__ __align__(16) bf16_t Wt[64][40];  // [n][k], 80 B rows (16B-aligned)
  const int tid = threadIdx.x;
  const int w = tid >> 6, lane = tid & 63, q4 = lane >> 4, li = lane & 15;
  const int n0 = blockIdx.x * 64;
  const int rowg = blockIdx.y;
  const int row = rowg * 64 + w * 16 + li;

  f32x4 acc[4];
#pragma unroll
  for (int i = 0; i < 4; ++i) acc[i] = (f32x4){0.f, 0.f, 0.f, 0.f};

  for (int k0 = 0; k0 < D_; k0 += 32) {
    __syncthreads();
#pragma unroll
    for (int p = 0; p < 2; ++p) {
      int idx = p * 256 + tid;
      int kk = idx >> 4, nn4 = (idx & 15) * 4;
      f32x4 w4 = *(const f32x4*)(W + (long)(k0 + kk) * N + n0 + nn4);
#pragma unroll
      for (int i = 0; i < 4; ++i) Wt[nn4 + i][kk] = (bf16_t)w4[i];
    }
    __syncthreads();
    bf16x8 av;
    if (ABF16) {
      av = *(const bf16x8*)((const bf16_t*)Ap_ + (long)row * D_ + k0 + q4 * 8);
    } else {
      const float* ap = (const float*)Ap_ + (long)row * D_ + k0 + q4 * 8;
      f32x4 a0 = *(const f32x4*)ap;
      f32x4 a1 = *(const f32x4*)(ap + 4);
      av = cvt8(a0, a1);
    }
#pragma unroll
    for (int cg = 0; cg < 4; ++cg) {
      bf16x8 bv = *(const bf16x8*)(&Wt[cg * 16 + li][q4 * 8]);
      acc[cg] = mfma16(av, bv, acc[cg]);
    }
  }

#pragma unroll
  for (int cg = 0; cg < 4; ++cg) {
#pragma unroll
    for (int r = 0; r < 4; ++r) {
      int rr = rowg * 64 + w * 16 + q4 * 4 + r;  // C row = quad*4+reg
      int n = n0 + cg * 16 + li;                 // C col = lane&15
      float v = acc[cg][r] + bias[n];
      if (MODE == 0) {
        outp[(long)rr * D_ + n] = v;
      } else {
        if (n < D_) {
          qout[(long)rr * D_ + n] = (bf16_t)v;
        } else {
          int nn = n & (D_ - 1);
          int hh = nn >> 7, dd = nn & 127;
          int bb = rr >> 4, ss = rr & 15;
          long off = ((long)(bb * 16 + hh) * TL + CL + ss) * HD + dd;
          if (n < 2 * D_) khout[off] = v; else vhout[off] = v;
        }
      }
    }
  }
}

// ---------------------------------------------------------------------------
// Fused KV-copy + flash attention partials.
// Grid: 128 (b,h) x 17 chunks. Cache chunk = 256 keys (4 subtiles of 64);
// chunk 16 = the 16 new keys written by the QKV GEMM (reads kh/vh tail,
// no copy, causal mask). Each wave owns 16 keys of the subtile for QK and a
// 32-wide d-slice of O for PV. K loads double as the copy AND the B-frags.
// ---------------------------------------------------------------------------
__global__ __launch_bounds__(256)
void attn_k(const float* __restrict__ kc, const float* __restrict__ vc,
            const bf16_t* __restrict__ qw, float* __restrict__ khout,
            float* __restrict__ vhout, float* __restrict__ part) {
  const int blk = blockIdx.x;
  const int bh = blk / NCH, ch = blk - bh * NCH;
  const bool is_new = (ch == 16);
  const int tid = threadIdx.x;
  const int w = tid >> 6, lane = tid & 63, q4 = lane >> 4, li = lane & 15;
  const int b = bh >> 4, h = bh & 15;

  __shared__ float m_lds[16], l_lds[16], alpha_lds[16];
  __shared__ float maxw[4][16], sumw[4][16];
  __shared__ __align__(16) bf16_t Pbuf[16][72];  // 144 B rows, 16B-aligned

  // Q A-frags: lane holds Q[s=li][k0 + quad*8 + j]
  bf16x8 Aq[4];
  {
    const bf16_t* qp = qw + (long)(b * 16 + li) * D_ + h * HD + q4 * 8;
#pragma unroll
    for (int i = 0; i < 4; ++i) Aq[i] = *(const bf16x8*)(qp + i * 32);
  }
  f32x4 Ov0 = {0.f, 0.f, 0.f, 0.f}, Ov1 = {0.f, 0.f, 0.f, 0.f};
  if (tid < 16) { m_lds[tid] = -1e30f; l_lds[tid] = 0.f; }
  __syncthreads();

  const int nst = is_new ? 1 : 4;
  for (int st = 0; st < nst; ++st) {
    const int tloc = st * 64 + w * 16 + li;  // this lane's key row (local)

    // ---- K load (copy + B-frag) and V copy ----
    bf16x8 Bk[4];
    if (!is_new) {
      const float* kp = kc + ((long)bh * CL + ch * CHUNK + tloc) * HD;
      float* kq = khout + ((long)bh * TL + ch * CHUNK + tloc) * HD;
      const float* vp = vc + ((long)bh * CL + ch * CHUNK + tloc) * HD;
      float* vq = vhout + ((long)bh * TL + ch * CHUNK + tloc) * HD;
#pragma unroll
      for (int i = 0; i < 4; ++i) {
        int d0 = i * 32 + q4 * 8;
        f32x4 x0 = *(const f32x4*)(kp + d0);
        f32x4 x1 = *(const f32x4*)(kp + d0 + 4);
        *(f32x4*)(kq + d0) = x0;
        *(f32x4*)(kq + d0 + 4) = x1;
        Bk[i] = cvt8(x0, x1);
        f32x4 y0 = *(const f32x4*)(vp + d0);
        f32x4 y1 = *(const f32x4*)(vp + d0 + 4);
        *(f32x4*)(vq + d0) = y0;
        *(f32x4*)(vq + d0 + 4) = y1;
      }
    } else {
      const bool valid = tloc < S_;
      const float* kp = khout + ((long)bh * TL + CL + tloc) * HD;
#pragma unroll
      for (int i = 0; i < 4; ++i) {
        int d0 = i * 32 + q4 * 8;
        f32x4 x0 = {0.f, 0.f, 0.f, 0.f}, x1 = {0.f, 0.f, 0.f, 0.f};
        if (valid) { x0 = *(const f32x4*)(kp + d0); x1 = *(const f32x4*)(kp + d0 + 4); }
        Bk[i] = cvt8(x0, x1);
      }
    }

    // ---- QK^T (wave's 16-key group), scale, mask ----
    f32x4 c = {0.f, 0.f, 0.f, 0.f};
#pragma unroll
    for (int i = 0; i < 4; ++i) c = mfma16(Aq[i], Bk[i], c);
    float sv[4];
#pragma unroll
    for (int r = 0; r < 4; ++r) {
      float v = c[r] * SCALE;
      if (is_new) {
        int rowq = q4 * 4 + r, tl = w * 16 + li;
        if (tl > rowq) v = -1e30f;  // causal: key pos 4096+tl vs query 4096+rowq
      }
      sv[r] = v;
    }

    // ---- wave-local row max over 16 key-cols (lanes of a quad) ----
#pragma unroll
    for (int r = 0; r < 4; ++r) {
      float v = sv[r];
      v = fmaxf(v, __shfl_xor(v, 1));
      v = fmaxf(v, __shfl_xor(v, 2));
      v = fmaxf(v, __shfl_xor(v, 4));
      v = fmaxf(v, __shfl_xor(v, 8));
      if (li == 0) maxw[w][q4 * 4 + r] = v;
    }
    __syncthreads();  // B1
    if (tid < 16) {
      float mo = m_lds[tid];
      float mw = fmaxf(fmaxf(maxw[0][tid], maxw[1][tid]),
                       fmaxf(maxw[2][tid], maxw[3][tid]));
      float mn = fmaxf(mo, mw);
      alpha_lds[tid] = __expf(mo - mn);
      m_lds[tid] = mn;
    }
    __syncthreads();  // B2

    // ---- P = exp(S - m), partial row sums, write P to LDS (bf16) ----
    float pv[4];
#pragma unroll
    for (int r = 0; r < 4; ++r) {
      int rowq = q4 * 4 + r;
      float p = __expf(sv[r] - m_lds[rowq]);
      pv[r] = p;
      Pbuf[rowq][w * 16 + li] = (bf16_t)p;
    }
#pragma unroll
    for (int r = 0; r < 4; ++r) {
      float u = pv[r];
      u += __shfl_xor(u, 1);
      u += __shfl_xor(u, 2);
      u += __shfl_xor(u, 4);
      u += __shfl_xor(u, 8);
      if (li == 0) sumw[w][q4 * 4 + r] = u;
    }
    // rescale O accumulators by alpha[row]
#pragma unroll
    for (int r = 0; r < 4; ++r) {
      float a = alpha_lds[q4 * 4 + r];
      Ov0[r] *= a; Ov1[r] *= a;
    }

    // ---- V B-frags (wave's 32-wide d slice): lane = V[t=quad*8+j][d] ----
    bf16x8 Bv[2][2];
    if (!is_new) {
      const float* vb = vc + ((long)bh * CL + ch * CHUNK + st * 64) * HD;
#pragma unroll
      for (int kst = 0; kst < 2; ++kst)
#pragma unroll
        for (int cg = 0; cg < 2; ++cg) {
          int d = w * 32 + cg * 16 + li;
#pragma unroll
          for (int j = 0; j < 8; ++j) {
            int tl = kst * 32 + q4 * 8 + j;
            Bv[kst][cg][j] = (bf16_t)vb[(long)tl * HD + d];
          }
        }
    } else {
      const float* vb = vhout + ((long)bh * TL + CL) * HD;
#pragma unroll
      for (int kst = 0; kst < 2; ++kst)
#pragma unroll
        for (int cg = 0; cg < 2; ++cg) {
          int d = w * 32 + cg * 16 + li;
#pragma unroll
          for (int j = 0; j < 8; ++j) {
            int tl = kst * 32 + q4 * 8 + j;
            float v = (tl < S_) ? vb[(long)tl * HD + d] : 0.f;
            Bv[kst][cg][j] = (bf16_t)v;
          }
        }
    }
    __syncthreads();  // B3: Pbuf + sumw ready
    if (tid < 16)
      l_lds[tid] = l_lds[tid] * alpha_lds[tid] +
                   sumw[0][tid] + sumw[1][tid] + sumw[2][tid] + sumw[3][tid];

    // ---- PV: A-frags of P from LDS, accumulate O ----
    bf16x8 Ap0 = *(const bf16x8*)(&Pbuf[li][q4 * 8]);
    bf16x8 Ap1 = *(const bf16x8*)(&Pbuf[li][32 + q4 * 8]);
    Ov0 = mfma16(Ap0, Bv[0][0], Ov0);
    Ov0 = mfma16(Ap1, Bv[1][0], Ov0);
    Ov1 = mfma16(Ap0, Bv[0][1], Ov1);
    Ov1 = mfma16(Ap1, Bv[1][1], Ov1);
  }

  // ---- write chunk partial: m[16], l[16], O[16][128] ----
  float* pb = part + ((long)bh * NCH + ch) * PSTRIDE;
  if (tid < 16) { pb[tid] = m_lds[tid]; pb[16 + tid] = l_lds[tid]; }
#pragma unroll
  for (int r = 0; r < 4; ++r) {
    int rowq = q4 * 4 + r;
    pb[32 + rowq * HD + w * 32 + li] = Ov0[r];
    pb[32 + rowq * HD + w * 32 + 16 + li] = Ov1[r];
  }
}

// ---------------------------------------------------------------------------
// Combine 17 chunk-partials per (b,h) -> normalized ctx (bf16, [B,S,D] layout)
// ---------------------------------------------------------------------------
__global__ __launch_bounds__(256)
void combine_k(const float* __restrict__ part, bf16_t* __restrict__ ctx) {
  const int bh = blockIdx.x;
  const int tid = threadIdx.x;
  const int s = tid >> 4, d0 = (tid & 15) * 8;
  const float* pb = part + (long)bh * NCH * PSTRIDE;
  float mv[NCH];
  float M = -1e30f;
#pragma unroll
  for (int c = 0; c < NCH; ++c) { mv[c] = pb[c * PSTRIDE + s]; M = fmaxf(M, mv[c]); }
  float L = 0.f;
  f32x4 a0 = {0.f, 0.f, 0.f, 0.f}, a1 = {0.f, 0.f, 0.f, 0.f};
#pragma unroll
  for (int c = 0; c < NCH; ++c) {
    float wc = __expf(mv[c] - M);
    L += wc * pb[c * PSTRIDE + 16 + s];
    const float* ob = pb + c * PSTRIDE + 32 + s * HD + d0;
    f32x4 o0 = *(const f32x4*)ob;
    f32x4 o1 = *(const f32x4*)(ob + 4);
#pragma unroll
    for (int i = 0; i < 4; ++i) { a0[i] += wc * o0[i]; a1[i] += wc * o1[i]; }
  }
  float inv = 1.f / L;
  const int b = bh >> 4, h = bh & 15;
  bf16_t* cp = ctx + (long)(b * 16 + s) * D_ + h * HD + d0;
#pragma unroll
  for (int i = 0; i < 4; ++i) {
    cp[i] = (bf16_t)(a0[i] * inv);
    cp[4 + i] = (bf16_t)(a1[i] * inv);
  }
}

// ---------------------------------------------------------------------------
extern "C" void kernel_launch(void* const* d_in, const int* in_sizes, int n_in,
                              void* d_out, int out_size, void* d_ws, size_t ws_size,
                              hipStream_t stream) {
  const float* x  = (const float*)d_in[0];
  const float* kc = (const float*)d_in[1];
  const float* vc = (const float*)d_in[2];
  const float* Wa = (const float*)d_in[3];
  const float* ba = (const float*)d_in[4];
  const float* Wp = (const float*)d_in[5];
  const float* bp = (const float*)d_in[6];

  float* outp  = (float*)d_out;                       // [8,16,2048]
  float* khout = outp + (long)B_ * S_ * D_;           // [8,16,4112,128]
  float* vhout = khout + (long)B_ * H_ * TL * HD;     // [8,16,4112,128]

  bf16_t* qws   = (bf16_t*)d_ws;                              // 512 KB
  bf16_t* ctxws = (bf16_t*)((char*)d_ws + 524288);            // 512 KB
  float*  part  = (float*)((char*)d_ws + 1048576);            // ~18.1 MB

  // K1: QKV projection (writes q->ws bf16, new k/v -> kh/vh tails fp32)
  gemm_k<false, 1><<<dim3(96, 2), 256, 0, stream>>>(
      x, Wa, ba, qws, khout, vhout, nullptr, 3 * D_);
  // K2: fused KV copy + flash attention partials
  attn_k<<<128 * NCH, 256, 0, stream>>>(kc, vc, qws, khout, vhout, part);
  // K3: combine partials -> ctx (bf16)
  combine_k<<<128, 256, 0, stream>>>(part, ctxws);
  // K4: output projection
  gemm_k<true, 0><<<dim3(32, 2), 256, 0, stream>>>(
      ctxws, Wp, bp, nullptr, nullptr, nullptr, outp, D_);
}